// Round 2
// baseline (480.114 us; speedup 1.0000x reference)
//
#include <hip/hip_runtime.h>
#include <math.h>

#define NMODES 64
#define NKNOTS 8
#define NSTEPS 80
#define ROW    1088      // NMODES + NMODES*NKNOTS*2
#define ROW4   272       // ROW/4
#define PREDF  10240     // NMODES*NSTEPS*2 floats per batch row

// One block (256 threads) per batch row.
// Thread (m = tid>>2, q = tid&3) produces float4 outputs  m*40 + i*4 + q,
// i = 0..9.  t = 8i + 2q + e  =>  shift = i>>1 (compile-time), so the 16
// knot floats of mode m stay in registers with static indexing.
__launch_bounds__(256, 4)
__global__ void head_kernel(const float* __restrict__ inputs,
                            const float* __restrict__ x,
                            const float* __restrict__ y,
                            const float* __restrict__ yaw,
                            const float* __restrict__ centroids,
                            float* __restrict__ pred,
                            float* __restrict__ conf,
                            float* __restrict__ knots_out)
{
    __shared__ float s_in[ROW];
    __shared__ float s_rot[4];

    const int tid = threadIdx.x;
    const int b   = blockIdx.x;

    // ---- stage full input row (1088 floats = 272 float4), coalesced ----
    const float4* row4  = (const float4*)(inputs + (size_t)b * ROW);
    float4*       s_in4 = (float4*)s_in;
    s_in4[tid] = row4[tid];
    if (tid < ROW4 - 256) s_in4[256 + tid] = row4[256 + tid];

    if (tid == 0) {
        float sy, cy;
        sincosf(yaw[b], &sy, &cy);
        s_rot[0] = cy;
        s_rot[1] = sy;
        s_rot[2] = x[b];
        s_rot[3] = y[b];
    }
    __syncthreads();

    // ---- knots output: straight copy of inputs[b, 64:1088], coalesced ----
    ((float4*)(knots_out + (size_t)b * 1024))[tid] = s_in4[16 + tid];

    // ---- softmax over 64 modes (wave 0 only) ----
    if (tid < 64) {
        float v  = s_in[tid];
        float mx = v;
        #pragma unroll
        for (int off = 32; off > 0; off >>= 1)
            mx = fmaxf(mx, __shfl_xor(mx, off));
        float e = expf(v - mx);
        float sum = e;
        #pragma unroll
        for (int off = 32; off > 0; off >>= 1)
            sum += __shfl_xor(sum, off);
        conf[(size_t)b * NMODES + tid] = e / sum;
    }

    // ---- load this thread's mode knots into registers (4x ds_read_b128) ----
    const int m = tid >> 2;
    const int q = tid & 3;
    float kx[8], ky[8];
    {
        const float4* kn4 = (const float4*)(s_in + NMODES + m * 16);
        float4 a0 = kn4[0], a1 = kn4[1], a2 = kn4[2], a3 = kn4[3];
        kx[0] = a0.x; kx[1] = a0.y; kx[2] = a0.z; kx[3] = a0.w;
        kx[4] = a1.x; kx[5] = a1.y; kx[6] = a1.z; kx[7] = a1.w;
        ky[0] = a2.x; ky[1] = a2.y; ky[2] = a2.z; ky[3] = a2.w;
        ky[4] = a3.x; ky[5] = a3.y; ky[6] = a3.z; ky[7] = a3.w;
    }

    const float rc = s_rot[0], rs = s_rot[1], X = s_rot[2], Y = s_rot[3];
    const float qf = (float)q * 0.125f;         // (2q)/16
    const float4* cent4 = (const float4*)centroids;   // 40 KB, L2-resident
    float4* out4 = (float4*)(pred + (size_t)b * PREDF);
    const int colbase = m * 40 + q;

#define BSPLINE_PAIR(U, SH, CX, CY, OX, OY)                                   \
    {                                                                         \
        float u  = (U);                                                       \
        float u2 = u * u, u3 = u2 * u, omu = 1.0f - u;                        \
        float b0 = omu * omu * omu * (1.0f / 6.0f);                           \
        float b1 = (3.0f * u3 - 6.0f * u2 + 4.0f) * (1.0f / 6.0f);            \
        float b2 = (-3.0f * u3 + 3.0f * u2 + 3.0f * u + 1.0f) * (1.0f/6.0f);  \
        float b3 = u3 * (1.0f / 6.0f);                                        \
        float fx = b0 * kx[SH] + b1 * kx[(SH)+1] + b2 * kx[(SH)+2] +          \
                   b3 * kx[(SH)+3] + (CX);                                    \
        float fy = b0 * ky[SH] + b1 * ky[(SH)+1] + b2 * ky[(SH)+2] +          \
                   b3 * ky[(SH)+3] + (CY);                                    \
        (OX) = rc * fx - rs * fy + X;                                         \
        (OY) = rs * fx + rc * fy + Y;                                         \
    }

#define STEP(I, SH, TB)                                                       \
    {                                                                         \
        const int idx = colbase + (I) * 4;                                    \
        float4 cent = cent4[idx];                                             \
        float4 o;                                                             \
        BSPLINE_PAIR((TB) + qf,            SH, cent.x, cent.y, o.x, o.y);     \
        BSPLINE_PAIR((TB) + qf + 0.0625f,  SH, cent.z, cent.w, o.z, o.w);     \
        out4[idx] = o;                                                        \
    }

    STEP(0, 0, 0.0f)
    STEP(1, 0, 0.5f)
    STEP(2, 1, 0.0f)
    STEP(3, 1, 0.5f)
    STEP(4, 2, 0.0f)
    STEP(5, 2, 0.5f)
    STEP(6, 3, 0.0f)
    STEP(7, 3, 0.5f)
    STEP(8, 4, 0.0f)
    STEP(9, 4, 0.5f)

#undef STEP
#undef BSPLINE_PAIR
}

extern "C" void kernel_launch(void* const* d_in, const int* in_sizes, int n_in,
                              void* d_out, int out_size, void* d_ws, size_t ws_size,
                              hipStream_t stream)
{
    const float* inputs    = (const float*)d_in[0];
    const float* x         = (const float*)d_in[1];
    const float* y         = (const float*)d_in[2];
    const float* yaw       = (const float*)d_in[3];
    const float* centroids = (const float*)d_in[4];

    const int B = in_sizes[1];  // x has B elements

    float* pred      = (float*)d_out;
    float* conf      = pred + (size_t)B * NMODES * NSTEPS * 2;
    float* knots_out = conf + (size_t)B * NMODES;

    head_kernel<<<B, 256, 0, stream>>>(inputs, x, y, yaw, centroids,
                                       pred, conf, knots_out);
}

// Round 3
// 403.840 us; speedup vs baseline: 1.1889x; 1.1889x over previous
//
#include <hip/hip_runtime.h>
#include <math.h>

#define NMODES 64
#define NKNOTS 8
#define NSTEPS 80
#define ROW    1088      // NMODES + NMODES*NKNOTS*2
#define PREDF  10240     // NMODES*NSTEPS*2 floats per batch row

typedef float f4 __attribute__((ext_vector_type(4)));

// One block (256 threads) per batch row.
// Output mapping (R1 style, store-contiguous): float4 index idx = j*256+tid,
// j = 0..9; wave writes 1 KB contiguous per store instruction, block walks
// its 40 KB pred row front-to-back.  Knot taps come from a transposed LDS
// table s_kn[m][c][(x,y)] built directly from the global knots load.
__launch_bounds__(256, 4)
__global__ void head_kernel(const float* __restrict__ inputs,
                            const float* __restrict__ x,
                            const float* __restrict__ y,
                            const float* __restrict__ yaw,
                            const float* __restrict__ centroids,
                            float* __restrict__ pred,
                            float* __restrict__ conf,
                            float* __restrict__ knots_out)
{
    __shared__ float s_kn[NMODES * NKNOTS * 2];  // [m][c][d], float2 taps
    __shared__ float s_rot[4];

    const int tid = threadIdx.x;
    const int b   = blockIdx.x;

    // ---- knots: one global float4 per thread (coalesced), feed both the
    //      copy-out and the LDS transpose ----
    const f4* row4 = (const f4*)(inputs + (size_t)b * ROW);
    f4 kv = row4[16 + tid];                      // knot floats 4*tid .. +3
    __builtin_nontemporal_store(kv, (f4*)(knots_out + (size_t)b * 1024) + tid);
    {
        int g = tid * 4;                         // flat knot index 0..1023
        #pragma unroll
        for (int e = 0; e < 4; ++e) {
            int gg = g + e;
            int m  = gg >> 4;
            int rr = gg & 15;
            int d  = rr >> 3;
            int c  = rr & 7;
            s_kn[(m << 4) + (c << 1) + d] = kv[e];
        }
    }

    if (tid == 0) {
        float sy, cy;
        sincosf(yaw[b], &sy, &cy);
        s_rot[0] = cy;  s_rot[1] = sy;
        s_rot[2] = x[b]; s_rot[3] = y[b];
    }

    // ---- softmax over 64 modes: wave 0, straight from global ----
    if (tid < 64) {
        float v  = inputs[(size_t)b * ROW + tid];
        float mx = v;
        #pragma unroll
        for (int off = 32; off > 0; off >>= 1)
            mx = fmaxf(mx, __shfl_xor(mx, off));
        float e = expf(v - mx);
        float sum = e;
        #pragma unroll
        for (int off = 32; off > 0; off >>= 1)
            sum += __shfl_xor(sum, off);
        __builtin_nontemporal_store(e / sum, conf + (size_t)b * NMODES + tid);
    }

    __syncthreads();   // the only barrier

    const float rc = s_rot[0], rs = s_rot[1], X = s_rot[2], Y = s_rot[3];
    const f4* cent4 = (const f4*)centroids;      // 40 KB, L1/L2-resident
    f4* out4 = (f4*)(pred + (size_t)b * PREDF);

    // idx = m*40 + r, maintained incrementally (256 = 6*40 + 16)
    int m   = (tid * 205) >> 13;                 // tid/40 for tid<256
    int r   = tid - m * 40;
    int idx = tid;

    #pragma unroll 2
    for (int j = 0; j < 10; ++j) {
        const int   sh = r >> 3;                 // shared by both t of the f4
        const float u0 = (float)(r & 7) * 0.125f;
        const float u1 = u0 + 0.0625f;

        // 4 taps, each a float2 (x,y): 4x ds_read_b64, broadcast-heavy
        const float2* kp = (const float2*)(s_kn + (m << 4) + (sh << 1));
        float2 k0 = kp[0], k1 = kp[1], k2 = kp[2], k3 = kp[3];

        f4 cent = cent4[idx];
        f4 o;
        {
            float u2 = u0 * u0, u3 = u2 * u0, omu = 1.0f - u0;
            float b0 = omu * omu * omu * (1.0f / 6.0f);
            float b1 = 0.5f * u3 - u2 + (2.0f / 3.0f);
            float b2 = -0.5f * u3 + 0.5f * u2 + 0.5f * u0 + (1.0f / 6.0f);
            float b3 = u3 * (1.0f / 6.0f);
            float fx = b0 * k0.x + b1 * k1.x + b2 * k2.x + b3 * k3.x + cent.x;
            float fy = b0 * k0.y + b1 * k1.y + b2 * k2.y + b3 * k3.y + cent.y;
            o.x = rc * fx - rs * fy + X;
            o.y = rs * fx + rc * fy + Y;
        }
        {
            float u2 = u1 * u1, u3 = u2 * u1, omu = 1.0f - u1;
            float b0 = omu * omu * omu * (1.0f / 6.0f);
            float b1 = 0.5f * u3 - u2 + (2.0f / 3.0f);
            float b2 = -0.5f * u3 + 0.5f * u2 + 0.5f * u1 + (1.0f / 6.0f);
            float b3 = u3 * (1.0f / 6.0f);
            float fx = b0 * k0.x + b1 * k1.x + b2 * k2.x + b3 * k3.x + cent.z;
            float fy = b0 * k0.y + b1 * k1.y + b2 * k2.y + b3 * k3.y + cent.w;
            o.z = rc * fx - rs * fy + X;
            o.w = rs * fx + rc * fy + Y;
        }
        __builtin_nontemporal_store(o, out4 + idx);

        // advance: idx += 256  =>  m += 6, r += 16 (mod 40)
        idx += 256;
        r += 16; m += 6;
        if (r >= 40) { r -= 40; ++m; }
    }
}

extern "C" void kernel_launch(void* const* d_in, const int* in_sizes, int n_in,
                              void* d_out, int out_size, void* d_ws, size_t ws_size,
                              hipStream_t stream)
{
    const float* inputs    = (const float*)d_in[0];
    const float* x         = (const float*)d_in[1];
    const float* y         = (const float*)d_in[2];
    const float* yaw       = (const float*)d_in[3];
    const float* centroids = (const float*)d_in[4];

    const int B = in_sizes[1];  // x has B elements

    float* pred      = (float*)d_out;
    float* conf      = pred + (size_t)B * NMODES * NSTEPS * 2;
    float* knots_out = conf + (size_t)B * NMODES;

    head_kernel<<<B, 256, 0, stream>>>(inputs, x, y, yaw, centroids,
                                       pred, conf, knots_out);
}

// Round 4
// 394.393 us; speedup vs baseline: 1.2173x; 1.0240x over previous
//
#include <hip/hip_runtime.h>
#include <math.h>

#define NMODES 64
#define NKNOTS 8
#define NSTEPS 80
#define ROW    1088      // NMODES + NMODES*NKNOTS*2
#define PREDF  10240     // NMODES*NSTEPS*2 floats per batch row
#define RPB    4         // batch rows per block

typedef float f4 __attribute__((ext_vector_type(4)));

// Grid = B/RPB blocks x 256 threads. Each block stages RPB input rows once
// (amortizing the cold-load head latency), then runs ONE fused j-loop:
// basis weights computed once per (thread,j) and reused for all RPB rows.
// Store mapping unchanged from R1/R3: float4 idx = j*256+tid per row ->
// each wave store instruction covers 1KB contiguous.
__launch_bounds__(256, 4)
__global__ void head_kernel(const float* __restrict__ inputs,
                            const float* __restrict__ x,
                            const float* __restrict__ y,
                            const float* __restrict__ yaw,
                            const float* __restrict__ centroids,
                            float* __restrict__ pred,
                            float* __restrict__ conf,
                            float* __restrict__ knots_out)
{
    __shared__ float s_kn[RPB][NMODES * NKNOTS * 2];  // [m][c][(x,y)]
    __shared__ float s_rot[RPB][4];

    const int    tid = threadIdx.x;
    const size_t b0  = (size_t)blockIdx.x * RPB;

    // ---- stage all RPB rows (coalesced float4) ----
    f4    kv[RPB];
    float cv[RPB];
    #pragma unroll
    for (int k = 0; k < RPB; ++k) {
        const float* rowp = inputs + (b0 + k) * ROW;
        kv[k] = ((const f4*)rowp)[16 + tid];          // knot floats 4t..4t+3
        cv[k] = (tid < 64) ? rowp[tid] : 0.0f;        // logits
    }
    if (tid < RPB) {
        float sy, cw;
        sincosf(yaw[b0 + tid], &sy, &cw);
        s_rot[tid][0] = cw;          s_rot[tid][1] = sy;
        s_rot[tid][2] = x[b0 + tid]; s_rot[tid][3] = y[b0 + tid];
    }
    // ---- transpose knots into LDS: [m][c][d] float2 taps ----
    #pragma unroll
    for (int k = 0; k < RPB; ++k) {
        const int g = tid * 4;
        #pragma unroll
        for (int e = 0; e < 4; ++e) {
            const int gg = g + e;
            s_kn[k][((gg >> 4) << 4) + ((gg & 7) << 1) + ((gg >> 3) & 1)] = kv[k][e];
        }
    }
    __syncthreads();   // the only barrier

    // ---- knots copy-out (coalesced) ----
    #pragma unroll
    for (int k = 0; k < RPB; ++k)
        __builtin_nontemporal_store(kv[k], (f4*)(knots_out + (b0 + k) * 1024) + tid);

    // ---- softmax (wave 0), RPB rows ----
    if (tid < 64) {
        #pragma unroll
        for (int k = 0; k < RPB; ++k) {
            float v = cv[k], mx = v;
            #pragma unroll
            for (int off = 32; off > 0; off >>= 1)
                mx = fmaxf(mx, __shfl_xor(mx, off));
            float e = expf(v - mx), sum = e;
            #pragma unroll
            for (int off = 32; off > 0; off >>= 1)
                sum += __shfl_xor(sum, off);
            __builtin_nontemporal_store(e / sum, conf + (b0 + k) * NMODES + tid);
        }
    }

    // ---- rot params to registers ----
    float rc[RPB], rs[RPB], Xo[RPB], Yo[RPB];
    #pragma unroll
    for (int k = 0; k < RPB; ++k) {
        rc[k] = s_rot[k][0]; rs[k] = s_rot[k][1];
        Xo[k] = s_rot[k][2]; Yo[k] = s_rot[k][3];
    }

    const f4* cent4 = (const f4*)centroids;   // 40 KB, L1/L2-resident

    // idx = m*40 + r walked incrementally (256 = 6*40 + 16)
    int m   = (tid * 205) >> 13;              // tid/40 for tid<256
    int r   = tid - m * 40;
    int idx = tid;

    #pragma unroll
    for (int j = 0; j < 10; ++j) {
        const int   sh = r >> 3;              // same for both t in the f4
        const float u0 = (float)(r & 7) * 0.125f;
        const float u1 = u0 + 0.0625f;

        float w0[4], w1[4];
        {
            float u2 = u0 * u0, u3 = u2 * u0, omu = 1.0f - u0;
            w0[0] = omu * omu * omu * (1.0f / 6.0f);
            w0[1] = 0.5f * u3 - u2 + (2.0f / 3.0f);
            w0[2] = -0.5f * u3 + 0.5f * u2 + 0.5f * u0 + (1.0f / 6.0f);
            w0[3] = u3 * (1.0f / 6.0f);
        }
        {
            float u2 = u1 * u1, u3 = u2 * u1, omu = 1.0f - u1;
            w1[0] = omu * omu * omu * (1.0f / 6.0f);
            w1[1] = 0.5f * u3 - u2 + (2.0f / 3.0f);
            w1[2] = -0.5f * u3 + 0.5f * u2 + 0.5f * u1 + (1.0f / 6.0f);
            w1[3] = u3 * (1.0f / 6.0f);
        }

        const f4  cent = cent4[idx];
        const int kofs = (m << 4) + (sh << 1);

        #pragma unroll
        for (int k = 0; k < RPB; ++k) {
            const float2* kp = (const float2*)(&s_kn[k][kofs]);
            const float2 k0 = kp[0], k1 = kp[1], k2 = kp[2], k3 = kp[3];
            f4 o;
            {
                float fx = w0[0]*k0.x + w0[1]*k1.x + w0[2]*k2.x + w0[3]*k3.x + cent.x;
                float fy = w0[0]*k0.y + w0[1]*k1.y + w0[2]*k2.y + w0[3]*k3.y + cent.y;
                o.x = rc[k] * fx - rs[k] * fy + Xo[k];
                o.y = rs[k] * fx + rc[k] * fy + Yo[k];
            }
            {
                float fx = w1[0]*k0.x + w1[1]*k1.x + w1[2]*k2.x + w1[3]*k3.x + cent.z;
                float fy = w1[0]*k0.y + w1[1]*k1.y + w1[2]*k2.y + w1[3]*k3.y + cent.w;
                o.z = rc[k] * fx - rs[k] * fy + Xo[k];
                o.w = rs[k] * fx + rc[k] * fy + Yo[k];
            }
            __builtin_nontemporal_store(o, (f4*)(pred + (b0 + k) * PREDF) + idx);
        }

        idx += 256;
        r += 16; m += 6;
        if (r >= 40) { r -= 40; ++m; }
    }
}

extern "C" void kernel_launch(void* const* d_in, const int* in_sizes, int n_in,
                              void* d_out, int out_size, void* d_ws, size_t ws_size,
                              hipStream_t stream)
{
    const float* inputs    = (const float*)d_in[0];
    const float* x         = (const float*)d_in[1];
    const float* y         = (const float*)d_in[2];
    const float* yaw       = (const float*)d_in[3];
    const float* centroids = (const float*)d_in[4];

    const int B = in_sizes[1];  // x has B elements

    float* pred      = (float*)d_out;
    float* conf      = pred + (size_t)B * NMODES * NSTEPS * 2;
    float* knots_out = conf + (size_t)B * NMODES;

    head_kernel<<<B / RPB, 256, 0, stream>>>(inputs, x, y, yaw, centroids,
                                             pred, conf, knots_out);
}